// Round 11
// baseline (1126.761 us; speedup 1.0000x reference)
//
#include <hip/hip_runtime.h>
#include <hip/hip_bf16.h>

typedef __hip_bfloat16 bf16;
typedef short s16x8 __attribute__((ext_vector_type(8)));
typedef float fx4 __attribute__((ext_vector_type(4)));
typedef unsigned int u32;

#define DIM 4096
#define SEQ 2048
#define NH 32
#define HD 128

#define MFMA_BF16(a,b,c) __builtin_amdgcn_mfma_f32_16x16x32_bf16((a),(b),(c),0,0,0)

__device__ __forceinline__ void gload16(const bf16* g, const bf16* l) {
  __builtin_amdgcn_global_load_lds((const __attribute__((address_space(1))) u32*)g,
                                   (__attribute__((address_space(3))) u32*)l, 16, 0, 0);
}

// ---------------- fp32 -> bf16 bulk convert ----------------
__global__ void cvt_f32_bf16(const float* __restrict__ in, bf16* __restrict__ out, int n8)
{
  int i = blockIdx.x * blockDim.x + threadIdx.x;
  const int stride = gridDim.x * blockDim.x;
  for (; i < n8; i += stride) {
    fx4 a = ((const fx4*)in)[2 * i], b = ((const fx4*)in)[2 * i + 1];
    s16x8 o; bf16* op = (bf16*)&o;
    #pragma unroll
    for (int j = 0; j < 4; ++j) { op[j] = __float2bfloat16(a[j]); op[4 + j] = __float2bfloat16(b[j]); }
    ((s16x8*)out)[i] = o;
  }
}

// ---------------- gemm256: 256x256 tile, 8 waves, dbuf LDS, counted vmcnt ----------------
// split-MFMA pipelining: kk0 MFMA overlaps kk1 ds_reads (compiler-counted waits)
__global__ __launch_bounds__(512, 1)
void gemm256(const bf16* __restrict__ A, const bf16* __restrict__ W,
             const float* __restrict__ bias,
             const float* __restrict__ fcos, const float* __restrict__ fsin,
             void* __restrict__ outv, int mode)
{
  __shared__ __align__(16) bf16 As[2][256 * 64];
  __shared__ __align__(16) bf16 Bs[2][256 * 64];
  const int tid = threadIdx.x;
  const int wid = tid >> 6;            // 0..7
  const int lane = tid & 63;
  const int l15 = lane & 15, lg = lane >> 4;
  const int wm = wid >> 2, wn = wid & 3;          // wave grid 2 x 4
  const int brow = blockIdx.y * 256, bcol = blockIdx.x * 256;
  const int rsub = lane >> 3;
  const int scol = ((lane & 7) ^ rsub) * 8;       // pre-swizzled source col

  fx4 acc[8][4] = {};

  // prologue: stage K-tiles 0 and 1 (16 loads/thread in flight)
  #pragma unroll
  for (int tt = 0; tt < 2; ++tt) {
    #pragma unroll
    for (int j = 0; j < 4; ++j) {
      const int chunk = j * 8 + wid;
      const int row = chunk * 8 + rsub;
      gload16(A + (size_t)(brow + row) * DIM + tt * 64 + scol, &As[tt][chunk * 512]);
      gload16(W + (size_t)(bcol + row) * DIM + tt * 64 + scol, &Bs[tt][chunk * 512]);
    }
  }

  for (int t = 0; t < 64; ++t) {
    const int p = t & 1;
    if (t < 63) asm volatile("s_waitcnt vmcnt(8)" ::: "memory");
    else        asm volatile("s_waitcnt vmcnt(0)" ::: "memory");
    __builtin_amdgcn_s_barrier();          // buf p fully staged
    __builtin_amdgcn_sched_barrier(0);

    // issue all 24 fragment reads (kk0's 12 first)
    s16x8 afr[2][8], bfr[2][4];
    #pragma unroll
    for (int kk = 0; kk < 2; ++kk) {
      #pragma unroll
      for (int mi = 0; mi < 8; ++mi) {
        const int r = wm * 128 + mi * 16 + l15;
        afr[kk][mi] = *(const s16x8*)&As[p][r * 64 + ((((kk * 4 + lg)) ^ (r & 7)) << 3)];
      }
      #pragma unroll
      for (int nj = 0; nj < 4; ++nj) {
        const int r = wn * 64 + nj * 16 + l15;
        bfr[kk][nj] = *(const s16x8*)&Bs[p][r * 64 + ((((kk * 4 + lg)) ^ (r & 7)) << 3)];
      }
    }

    // MFMA kk0 — compiler auto-waits only on kk0's reads; kk1 reads land under it
    __builtin_amdgcn_s_setprio(1);
    #pragma unroll
    for (int mi = 0; mi < 8; ++mi)
      #pragma unroll
      for (int nj = 0; nj < 4; ++nj)
        acc[mi][nj] = MFMA_BF16(afr[0][mi], bfr[0][nj], acc[mi][nj]);
    __builtin_amdgcn_s_setprio(0);

    asm volatile("s_waitcnt lgkmcnt(0)" ::: "memory");   // all my reads of buf p done
    __builtin_amdgcn_sched_barrier(0);
    __builtin_amdgcn_s_barrier();          // ALL waves done reading buf p
    __builtin_amdgcn_sched_barrier(0);

    // stage K-tile t+2 into buf p (lands while we compute kk1)
    if (t + 2 < 64) {
      const int k0 = (t + 2) * 64;
      #pragma unroll
      for (int j = 0; j < 4; ++j) {
        const int chunk = j * 8 + wid;
        const int row = chunk * 8 + rsub;
        gload16(A + (size_t)(brow + row) * DIM + k0 + scol, &As[p][chunk * 512]);
        gload16(W + (size_t)(bcol + row) * DIM + k0 + scol, &Bs[p][chunk * 512]);
      }
    }

    __builtin_amdgcn_s_setprio(1);
    #pragma unroll
    for (int mi = 0; mi < 8; ++mi)
      #pragma unroll
      for (int nj = 0; nj < 4; ++nj)
        acc[mi][nj] = MFMA_BF16(afr[1][mi], bfr[1][nj], acc[mi][nj]);
    __builtin_amdgcn_s_setprio(0);
  }

  // epilogue
  #pragma unroll
  for (int mi = 0; mi < 8; ++mi) {
    const int mbase = brow + wm * 128 + mi * 16 + lg * 4;
    #pragma unroll
    for (int nj = 0; nj < 4; ++nj) {
      const int n = bcol + wn * 64 + nj * 16 + l15;
      const float bv = bias[n];
      #pragma unroll
      for (int r = 0; r < 4; ++r) {
        const int m = mbase + r;
        float val = acc[mi][nj][r] + bv;
        if (mode <= 1) {
          const float pv = __shfl_xor(val, 1);
          const int sp = m & (SEQ - 1);
          const int fi = (n >> 1) & 63;
          const float c = fcos[sp * 64 + fi];
          const float s = fsin[sp * 64 + fi];
          val = (n & 1) ? (pv * s + val * c) : (val * c - pv * s);
        }
        if (mode == 3) {
          ((float*)outv)[(size_t)m * DIM + n] = val;
        } else {
          const int b = m >> 11, sp = m & (SEQ - 1);
          const int h = n >> 7, d = n & (HD - 1);
          ((bf16*)outv)[((size_t)(b * NH + h) * SEQ + sp) * HD + d] = __float2bfloat16(val);
        }
      }
    }
  }
}

// ---------------- slow fallback GEMM (fp32 inputs, reg-staged) ----------------
__global__ __launch_bounds__(256, 2)
void gemm_slow(const void* __restrict__ Av, const float* __restrict__ Wf,
               const float* __restrict__ bias,
               const float* __restrict__ fcos, const float* __restrict__ fsin,
               void* __restrict__ outv, int mode)
{
  __shared__ __align__(16) bf16 As[128 * 64];
  __shared__ __align__(16) bf16 Bs[128 * 64];
  const int abf = (mode == 3) ? 1 : 0;
  const int tid = threadIdx.x;
  const int wid = tid >> 6;
  const int lane = tid & 63;
  const int l15 = lane & 15, lg = lane >> 4;
  const int wr = wid >> 1, wc = wid & 1;
  const int brow = blockIdx.y * 128, bcol = blockIdx.x * 128;

  fx4 acc[4][4] = {};

  for (int k0 = 0; k0 < DIM; k0 += 64) {
    #pragma unroll
    for (int i = 0; i < 4; ++i) {
      const int v = i * 256 + tid;
      const int row = v >> 3;
      const int c8 = (v & 7) * 8;
      s16x8 a, b;
      if (abf) {
        a = *(const s16x8*)&((const bf16*)Av)[(size_t)(brow + row) * DIM + k0 + c8];
      } else {
        const float* Af = (const float*)Av;
        fx4 a0 = *(const fx4*)&Af[(size_t)(brow + row) * DIM + k0 + c8];
        fx4 a1 = *(const fx4*)&Af[(size_t)(brow + row) * DIM + k0 + c8 + 4];
        bf16* ap = (bf16*)&a;
        #pragma unroll
        for (int j = 0; j < 4; ++j) { ap[j] = __float2bfloat16(a0[j]); ap[4 + j] = __float2bfloat16(a1[j]); }
      }
      {
        fx4 b0 = *(const fx4*)&Wf[(size_t)(bcol + row) * DIM + k0 + c8];
        fx4 b1 = *(const fx4*)&Wf[(size_t)(bcol + row) * DIM + k0 + c8 + 4];
        bf16* bp = (bf16*)&b;
        #pragma unroll
        for (int j = 0; j < 4; ++j) { bp[j] = __float2bfloat16(b0[j]); bp[4 + j] = __float2bfloat16(b1[j]); }
      }
      *(s16x8*)&As[row * 64 + c8] = a;
      *(s16x8*)&Bs[row * 64 + c8] = b;
    }
    __syncthreads();
    #pragma unroll
    for (int kk = 0; kk < 2; ++kk) {
      s16x8 af[4], bfr[4];
      #pragma unroll
      for (int mi = 0; mi < 4; ++mi)
        af[mi] = *(const s16x8*)&As[(wr * 64 + mi * 16 + l15) * 64 + kk * 32 + lg * 8];
      #pragma unroll
      for (int nj = 0; nj < 4; ++nj)
        bfr[nj] = *(const s16x8*)&Bs[(wc * 64 + nj * 16 + l15) * 64 + kk * 32 + lg * 8];
      #pragma unroll
      for (int mi = 0; mi < 4; ++mi)
        #pragma unroll
        for (int nj = 0; nj < 4; ++nj)
          acc[mi][nj] = MFMA_BF16(af[mi], bfr[nj], acc[mi][nj]);
    }
    __syncthreads();
  }

  #pragma unroll
  for (int mi = 0; mi < 4; ++mi) {
    const int mbase = brow + wr * 64 + mi * 16 + lg * 4;
    #pragma unroll
    for (int nj = 0; nj < 4; ++nj) {
      const int n = bcol + wc * 64 + nj * 16 + l15;
      const float bv = bias[n];
      #pragma unroll
      for (int r = 0; r < 4; ++r) {
        const int m = mbase + r;
        float val = acc[mi][nj][r] + bv;
        if (mode <= 1) {
          const float pv = __shfl_xor(val, 1);
          const int sp = m & (SEQ - 1);
          const int fi = (n >> 1) & 63;
          const float c = fcos[sp * 64 + fi];
          const float s = fsin[sp * 64 + fi];
          val = (n & 1) ? (pv * s + val * c) : (val * c - pv * s);
        }
        if (mode == 3) {
          ((float*)outv)[(size_t)m * DIM + n] = val;
        } else {
          const int b = m >> 11, sp = m & (SEQ - 1);
          const int h = n >> 7, d = n & (HD - 1);
          ((bf16*)outv)[((size_t)(b * NH + h) * SEQ + sp) * HD + d] = __float2bfloat16(val);
        }
      }
    }
  }
}

// ---------------- causal flash attention: 48KB LDS, Pl aliased into Kl ----------------
// Per-wave Pl regions are only ever read by the owning wave -> alias into Kl
// (safe after B2). Sequential B-then-A softmax/PV. 3 barriers/tile, 3 blocks/CU.
#define SOFTMAX_PHASE(sa, o, mrun, lrun, q0)                                   \
  {                                                                            \
    _Pragma("unroll")                                                          \
    for (int r = 0; r < 4; ++r) {                                              \
      const int q = (q0) + lg * 4 + r;                                         \
      float mx = -__builtin_inff();                                            \
      _Pragma("unroll")                                                        \
      for (int nj = 0; nj < 4; ++nj) {                                         \
        float v = sa[nj][r] * scale;                                           \
        if (diagM && (t0 + nj * 16 + l15 > q)) v = -__builtin_inff();          \
        sa[nj][r] = v;                                                         \
        mx = fmaxf(mx, v);                                                     \
      }                                                                        \
      _Pragma("unroll")                                                        \
      for (int off = 1; off < 16; off <<= 1) mx = fmaxf(mx, __shfl_xor(mx, off)); \
      const float mnew = fmaxf(mrun[r], mx);                                   \
      const float fsc = __expf(mrun[r] - mnew);                                \
      mrun[r] = mnew;                                                          \
      float rs = 0.f;                                                          \
      _Pragma("unroll")                                                        \
      for (int nj = 0; nj < 4; ++nj) {                                         \
        const float pp = __expf(sa[nj][r] - mnew);                             \
        sa[nj][r] = pp;                                                        \
        rs += pp;                                                              \
      }                                                                        \
      _Pragma("unroll")                                                        \
      for (int off = 1; off < 16; off <<= 1) rs += __shfl_xor(rs, off);        \
      lrun[r] = lrun[r] * fsc + rs;                                            \
      _Pragma("unroll")                                                        \
      for (int dj = 0; dj < 8; ++dj) o[dj][r] *= fsc;                          \
    }                                                                          \
  }

__global__ __launch_bounds__(256, 3)
void attn_fwd(const bf16* __restrict__ Q, const bf16* __restrict__ K,
              const bf16* __restrict__ V, bf16* __restrict__ ymat)
{
  __shared__ __align__(16) bf16 smem[24576];   // 48 KB
  bf16* Kl   = smem;                  // [64][128]  16 KB
  bf16* Vrow = smem + 8192;           // [64][128]  16 KB
  bf16* Vt   = smem + 16384;          // [128][64]  16 KB
  bf16* Ys   = smem;                  // epilogue alias [64][256] 32 KB

  const int tid = threadIdx.x, wid = tid >> 6, lane = tid & 63;
  const int l15 = lane & 15, lg = lane >> 4;
  bf16* Pl = Kl + wid * 1024;         // per-wave 2KB region, aliased into Kl

  const int pair = blockIdx.x, bh = blockIdx.y;
  const int qtA = pair, qtB = 31 - pair;
  const int b = bh >> 5, h = bh & 31;
  const bf16* Qb = Q + (size_t)bh * SEQ * HD;
  const bf16* Kb = K + (size_t)bh * SEQ * HD;
  const bf16* Vb = V + (size_t)bh * SEQ * HD;
  const int q0A = qtA * 64 + wid * 16;
  const int q0B = qtB * 64 + wid * 16;

  s16x8 aqA[4], aqB[4];
  #pragma unroll
  for (int kk = 0; kk < 4; ++kk) {
    aqA[kk] = *(const s16x8*)&Qb[(size_t)(q0A + l15) * HD + kk * 32 + lg * 8];
    aqB[kk] = *(const s16x8*)&Qb[(size_t)(q0B + l15) * HD + kk * 32 + lg * 8];
  }

  fx4 oA[8] = {}, oB[8] = {};
  float mA[4], lA[4], mB[4], lB[4];
  #pragma unroll
  for (int r = 0; r < 4; ++r) {
    mA[r] = -__builtin_inff(); lA[r] = 0.f;
    mB[r] = -__builtin_inff(); lB[r] = 0.f;
  }
  const float scale = 0.08838834764831845f;

  for (int kt = 0; kt <= qtB; ++kt) {
    const int t0 = kt * 64;
    const bool doA = (kt <= qtA);     // block-uniform

    // stage K + V rows (pre-swizzled global source -> linear LDS dest)
    #pragma unroll
    for (int i = 0; i < 4; ++i) {
      const int chunk = i * 4 + wid;
      const int row = chunk * 4 + lg;
      const int col = ((l15 ^ (row & 7)) * 8);
      gload16(Kb + (size_t)(t0 + row) * HD + col, Kl + chunk * 512);
      gload16(Vb + (size_t)(t0 + row) * HD + col, Vrow + chunk * 512);
    }
    __syncthreads();   // B1

    // QK^T for both q-sets
    fx4 sA[4], sB[4];
    #pragma unroll
    for (int nj = 0; nj < 4; ++nj) {
      fx4 sa = {}, sb = {};
      #pragma unroll
      for (int kk = 0; kk < 4; ++kk) {
        const int trow = nj * 16 + l15;
        const int colp = (kk * 32 + lg * 8) ^ ((trow & 7) << 3);
        s16x8 bk = *(const s16x8*)&Kl[trow * HD + colp];
        sb = MFMA_BF16(aqB[kk], bk, sb);
        if (doA) sa = MFMA_BF16(aqA[kk], bk, sa);
      }
      sB[nj] = sb; sA[nj] = sa;
    }

    // V transpose Vrow -> Vt
    #pragma unroll
    for (int it = 0; it < 2; ++it) {
      const int p = lane;
      const int tg = it * 4 + wid;
      s16x8 lo, hi; bf16* lop = (bf16*)&lo; bf16* hip = (bf16*)&hi;
      #pragma unroll
      for (int j = 0; j < 8; ++j) {
        const int t = tg * 8 + j;
        const u32 v32 = *(const u32*)((const char*)Vrow + t * 256 + ((p * 4) ^ (j << 4)));
        lop[j] = ((const bf16*)&v32)[0];
        hip[j] = ((const bf16*)&v32)[1];
      }
      *(s16x8*)((char*)Vt + (2 * p) * 128 + ((tg * 16) ^ ((p & 7) << 4))) = lo;
      *(s16x8*)((char*)Vt + (2 * p + 1) * 128 + ((tg * 16) ^ ((p & 7) << 4))) = hi;
    }
    __syncthreads();   // B2: Kl reads done (Pl alias safe), Vt ready

    // ---- B path: softmax -> Pl -> PV ----
    {
      const bool diagM = (kt == qtB);
      SOFTMAX_PHASE(sB, oB, mB, lB, q0B)
      #pragma unroll
      for (int r = 0; r < 4; ++r) {
        const int row = lg * 4 + r;
        #pragma unroll
        for (int nj = 0; nj < 4; ++nj) {
          const int colp = (nj * 16 + l15) ^ ((row & 7) << 3);
          Pl[row * 64 + colp] = __float2bfloat16(sB[nj][r]);
        }
      }
      s16x8 pa[2];
      #pragma unroll
      for (int k2 = 0; k2 < 2; ++k2) {
        const int colp = (k2 * 32 + lg * 8) ^ ((l15 & 7) << 3);
        pa[k2] = *(const s16x8*)&Pl[l15 * 64 + colp];
      }
      #pragma unroll
      for (int dj = 0; dj < 8; ++dj) {
        const int d = dj * 16 + l15;
        #pragma unroll
        for (int k2 = 0; k2 < 2; ++k2) {
          const int colp = (k2 * 32 + lg * 8) ^ (((d >> 1) & 7) << 3);
          s16x8 bv = *(const s16x8*)&Vt[d * 64 + colp];
          oB[dj] = MFMA_BF16(pa[k2], bv, oB[dj]);
        }
      }
    }
    // ---- A path (same Pl region; same-wave write-after-read is compiler-ordered) ----
    if (doA) {
      const bool diagM = (kt == qtA);
      SOFTMAX_PHASE(sA, oA, mA, lA, q0A)
      #pragma unroll
      for (int r = 0; r < 4; ++r) {
        const int row = lg * 4 + r;
        #pragma unroll
        for (int nj = 0; nj < 4; ++nj) {
          const int colp = (nj * 16 + l15) ^ ((row & 7) << 3);
          Pl[row * 64 + colp] = __float2bfloat16(sA[nj][r]);
        }
      }
      s16x8 pa[2];
      #pragma unroll
      for (int k2 = 0; k2 < 2; ++k2) {
        const int colp = (k2 * 32 + lg * 8) ^ ((l15 & 7) << 3);
        pa[k2] = *(const s16x8*)&Pl[l15 * 64 + colp];
      }
      #pragma unroll
      for (int dj = 0; dj < 8; ++dj) {
        const int d = dj * 16 + l15;
        #pragma unroll
        for (int k2 = 0; k2 < 2; ++k2) {
          const int colp = (k2 * 32 + lg * 8) ^ (((d >> 1) & 7) << 3);
          s16x8 bv = *(const s16x8*)&Vt[d * 64 + colp];
          oA[dj] = MFMA_BF16(pa[k2], bv, oA[dj]);
        }
      }
    }
    __syncthreads();   // B3: safe to overwrite Kl(+Pl)/Vrow next iter
  }

  // epilogue: LDS-staged, full-line ymat writes
  #pragma unroll
  for (int dj = 0; dj < 8; ++dj) {
    const int d = dj * 16 + l15;
    const int lr = d >> 1;
    const int cbase = (d & 1) * 128 + wid * 16 + lg * 4;
    const int sw = (lr & 7) << 3;
    #pragma unroll
    for (int r = 0; r < 4; ++r) {
      Ys[lr * 256 + ((cbase + r) ^ sw)]       = __float2bfloat16(oA[dj][r] / lA[r]);
      Ys[lr * 256 + ((cbase + 64 + r) ^ sw)]  = __float2bfloat16(oB[dj][r] / lB[r]);
    }
  }
  __syncthreads();

  const size_t growbase = (size_t)(b * SEQ + h * 64) * DIM;
  #pragma unroll
  for (int it = 0; it < 8; ++it) {
    const int f = it * 256 + tid;
    const int lr = f >> 5;
    const int cu = f & 31;
    s16x8 v = *(const s16x8*)&Ys[lr * 256 + ((cu ^ (lr & 7)) << 3)];
    const int seg = cu >> 3;
    const int off = (cu & 7) * 8;
    const int par = seg >> 1, ab = seg & 1;
    const int qbase = (ab ? qtB : qtA) * 64;
    *(s16x8*)&ymat[growbase + (size_t)lr * DIM + par * 2048 + qbase + off] = v;
  }
}

extern "C" void kernel_launch(void* const* d_in, const int* in_sizes, int n_in,
                              void* d_out, int out_size, void* d_ws, size_t ws_size,
                              hipStream_t stream)
{
  (void)in_sizes; (void)n_in; (void)out_size;
  const float* x  = (const float*)d_in[0];
  const float* wq = (const float*)d_in[1];
  const float* bq = (const float*)d_in[2];
  const float* wk = (const float*)d_in[3];
  const float* bk = (const float*)d_in[4];
  const float* wv = (const float*)d_in[5];
  const float* bv = (const float*)d_in[6];
  const float* wo = (const float*)d_in[7];
  const float* bo = (const float*)d_in[8];
  const float* fc = (const float*)d_in[9];
  const float* fs = (const float*)d_in[10];

  const size_t NE = (size_t)2 * SEQ * DIM;
  const size_t NW = (size_t)DIM * DIM;
  const size_t SLOT = NE * sizeof(bf16);
  const size_t NEED_FAST = 6 * SLOT + 256;
  const size_t NEED_SLOW = 4 * SLOT + 256;

  dim3 blk(256);
  if (ws_size >= NEED_FAST) {
    bf16* xb = (bf16*)((char*)d_ws + 256);
    bf16* wb = xb + NE;
    bf16* qb = wb + NW;
    bf16* kb = qb + NE;
    bf16* vb = kb + NE;
    bf16* ym = vb + NE;
    const int n8x = (int)(NE / 8), n8w = (int)(NW / 8);
    dim3 cg(2048);
    dim3 blk2(512), gg2(16, 16);
    hipLaunchKernelGGL(cvt_f32_bf16, cg, blk, 0, stream, x, xb, n8x);
    hipLaunchKernelGGL(cvt_f32_bf16, cg, blk, 0, stream, wq, wb, n8w);
    hipLaunchKernelGGL(gemm256, gg2, blk2, 0, stream, xb, wb, bq, fc, fs, qb, 0);
    hipLaunchKernelGGL(cvt_f32_bf16, cg, blk, 0, stream, wk, wb, n8w);
    hipLaunchKernelGGL(gemm256, gg2, blk2, 0, stream, xb, wb, bk, fc, fs, kb, 1);
    hipLaunchKernelGGL(cvt_f32_bf16, cg, blk, 0, stream, wv, wb, n8w);
    hipLaunchKernelGGL(gemm256, gg2, blk2, 0, stream, xb, wb, bv, fc, fs, vb, 2);
    hipLaunchKernelGGL(attn_fwd, dim3(16, 64), blk, 0, stream, qb, kb, vb, ym);
    hipLaunchKernelGGL(cvt_f32_bf16, cg, blk, 0, stream, wo, wb, n8w);
    hipLaunchKernelGGL(gemm256, gg2, blk2, 0, stream, ym, wb, bo, fc, fs, d_out, 3);
  } else if (ws_size >= NEED_SLOW) {
    bf16* qb = (bf16*)((char*)d_ws + 256);
    bf16* kb = qb + NE;
    bf16* vb = kb + NE;
    bf16* ym = vb + NE;
    dim3 gg(32, 32);
    hipLaunchKernelGGL(gemm_slow, gg, blk, 0, stream, x, wq, bq, fc, fs, qb, 0);
    hipLaunchKernelGGL(gemm_slow, gg, blk, 0, stream, x, wk, bk, fc, fs, kb, 1);
    hipLaunchKernelGGL(gemm_slow, gg, blk, 0, stream, x, wv, bv, fc, fs, vb, 2);
    hipLaunchKernelGGL(attn_fwd, dim3(16, 64), blk, 0, stream, qb, kb, vb, ym);
    hipLaunchKernelGGL(gemm_slow, gg, blk, 0, stream, ym, wo, bo, fc, fs, d_out, 3);
  }
}

// Round 12
// 867.465 us; speedup vs baseline: 1.2989x; 1.2989x over previous
//
#include <hip/hip_runtime.h>
#include <hip/hip_bf16.h>

typedef __hip_bfloat16 bf16;
typedef short s16x8 __attribute__((ext_vector_type(8)));
typedef float fx4 __attribute__((ext_vector_type(4)));
typedef unsigned int u32;

#define DIM 4096
#define SEQ 2048
#define NH 32
#define HD 128

#define MFMA_BF16(a,b,c) __builtin_amdgcn_mfma_f32_16x16x32_bf16((a),(b),(c),0,0,0)

__device__ __forceinline__ void gload16(const bf16* g, const bf16* l) {
  __builtin_amdgcn_global_load_lds((const __attribute__((address_space(1))) u32*)g,
                                   (__attribute__((address_space(3))) u32*)l, 16, 0, 0);
}

// ---------------- fp32 -> bf16 bulk convert ----------------
__global__ void cvt_f32_bf16(const float* __restrict__ in, bf16* __restrict__ out, int n8)
{
  int i = blockIdx.x * blockDim.x + threadIdx.x;
  const int stride = gridDim.x * blockDim.x;
  for (; i < n8; i += stride) {
    fx4 a = ((const fx4*)in)[2 * i], b = ((const fx4*)in)[2 * i + 1];
    s16x8 o; bf16* op = (bf16*)&o;
    #pragma unroll
    for (int j = 0; j < 4; ++j) { op[j] = __float2bfloat16(a[j]); op[4 + j] = __float2bfloat16(b[j]); }
    ((s16x8*)out)[i] = o;
  }
}

// ---------------- gemm256 (exact R10): 256x256 tile, 8 waves, dbuf, counted vmcnt ----
__global__ __launch_bounds__(512, 1)
void gemm256(const bf16* __restrict__ A, const bf16* __restrict__ W,
             const float* __restrict__ bias,
             const float* __restrict__ fcos, const float* __restrict__ fsin,
             void* __restrict__ outv, int mode)
{
  __shared__ __align__(16) bf16 As[2][256 * 64];
  __shared__ __align__(16) bf16 Bs[2][256 * 64];
  const int tid = threadIdx.x;
  const int wid = tid >> 6;            // 0..7
  const int lane = tid & 63;
  const int l15 = lane & 15, lg = lane >> 4;
  const int wm = wid >> 2, wn = wid & 3;          // wave grid 2 x 4
  const int brow = blockIdx.y * 256, bcol = blockIdx.x * 256;
  const int rsub = lane >> 3;
  const int scol = ((lane & 7) ^ rsub) * 8;       // pre-swizzled source col

  fx4 acc[8][4] = {};

  #pragma unroll
  for (int tt = 0; tt < 2; ++tt) {
    #pragma unroll
    for (int j = 0; j < 4; ++j) {
      const int chunk = j * 8 + wid;
      const int row = chunk * 8 + rsub;
      gload16(A + (size_t)(brow + row) * DIM + tt * 64 + scol, &As[tt][chunk * 512]);
      gload16(W + (size_t)(bcol + row) * DIM + tt * 64 + scol, &Bs[tt][chunk * 512]);
    }
  }

  for (int t = 0; t < 64; ++t) {
    const int p = t & 1;
    if (t < 63) asm volatile("s_waitcnt vmcnt(8)" ::: "memory");
    else        asm volatile("s_waitcnt vmcnt(0)" ::: "memory");
    __builtin_amdgcn_s_barrier();          // buf p fully staged
    __builtin_amdgcn_sched_barrier(0);

    s16x8 afr[2][8], bfr[2][4];
    #pragma unroll
    for (int kk = 0; kk < 2; ++kk) {
      #pragma unroll
      for (int mi = 0; mi < 8; ++mi) {
        const int r = wm * 128 + mi * 16 + l15;
        afr[kk][mi] = *(const s16x8*)&As[p][r * 64 + ((((kk * 4 + lg)) ^ (r & 7)) << 3)];
      }
      #pragma unroll
      for (int nj = 0; nj < 4; ++nj) {
        const int r = wn * 64 + nj * 16 + l15;
        bfr[kk][nj] = *(const s16x8*)&Bs[p][r * 64 + ((((kk * 4 + lg)) ^ (r & 7)) << 3)];
      }
    }
    asm volatile("s_waitcnt lgkmcnt(0)" ::: "memory");
    __builtin_amdgcn_sched_barrier(0);
    __builtin_amdgcn_s_barrier();          // ALL waves done reading buf p
    __builtin_amdgcn_sched_barrier(0);

    if (t + 2 < 64) {
      const int k0 = (t + 2) * 64;
      #pragma unroll
      for (int j = 0; j < 4; ++j) {
        const int chunk = j * 8 + wid;
        const int row = chunk * 8 + rsub;
        gload16(A + (size_t)(brow + row) * DIM + k0 + scol, &As[p][chunk * 512]);
        gload16(W + (size_t)(bcol + row) * DIM + k0 + scol, &Bs[p][chunk * 512]);
      }
    }

    __builtin_amdgcn_s_setprio(1);
    #pragma unroll
    for (int kk = 0; kk < 2; ++kk)
      #pragma unroll
      for (int mi = 0; mi < 8; ++mi)
        #pragma unroll
        for (int nj = 0; nj < 4; ++nj)
          acc[mi][nj] = MFMA_BF16(afr[kk][mi], bfr[kk][nj], acc[mi][nj]);
    __builtin_amdgcn_s_setprio(0);
  }

  #pragma unroll
  for (int mi = 0; mi < 8; ++mi) {
    const int mbase = brow + wm * 128 + mi * 16 + lg * 4;
    #pragma unroll
    for (int nj = 0; nj < 4; ++nj) {
      const int n = bcol + wn * 64 + nj * 16 + l15;
      const float bv = bias[n];
      #pragma unroll
      for (int r = 0; r < 4; ++r) {
        const int m = mbase + r;
        float val = acc[mi][nj][r] + bv;
        if (mode <= 1) {
          const float pv = __shfl_xor(val, 1);
          const int sp = m & (SEQ - 1);
          const int fi = (n >> 1) & 63;
          const float c = fcos[sp * 64 + fi];
          const float s = fsin[sp * 64 + fi];
          val = (n & 1) ? (pv * s + val * c) : (val * c - pv * s);
        }
        if (mode == 3) {
          ((float*)outv)[(size_t)m * DIM + n] = val;
        } else {
          const int b = m >> 11, sp = m & (SEQ - 1);
          const int h = n >> 7, d = n & (HD - 1);
          ((bf16*)outv)[((size_t)(b * NH + h) * SEQ + sp) * HD + d] = __float2bfloat16(val);
        }
      }
    }
  }
}

// ---------------- slow fallback GEMM (fp32 inputs, reg-staged) ----------------
__global__ __launch_bounds__(256, 2)
void gemm_slow(const void* __restrict__ Av, const float* __restrict__ Wf,
               const float* __restrict__ bias,
               const float* __restrict__ fcos, const float* __restrict__ fsin,
               void* __restrict__ outv, int mode)
{
  __shared__ __align__(16) bf16 As[128 * 64];
  __shared__ __align__(16) bf16 Bs[128 * 64];
  const int abf = (mode == 3) ? 1 : 0;
  const int tid = threadIdx.x;
  const int wid = tid >> 6;
  const int lane = tid & 63;
  const int l15 = lane & 15, lg = lane >> 4;
  const int wr = wid >> 1, wc = wid & 1;
  const int brow = blockIdx.y * 128, bcol = blockIdx.x * 128;

  fx4 acc[4][4] = {};

  for (int k0 = 0; k0 < DIM; k0 += 64) {
    #pragma unroll
    for (int i = 0; i < 4; ++i) {
      const int v = i * 256 + tid;
      const int row = v >> 3;
      const int c8 = (v & 7) * 8;
      s16x8 a, b;
      if (abf) {
        a = *(const s16x8*)&((const bf16*)Av)[(size_t)(brow + row) * DIM + k0 + c8];
      } else {
        const float* Af = (const float*)Av;
        fx4 a0 = *(const fx4*)&Af[(size_t)(brow + row) * DIM + k0 + c8];
        fx4 a1 = *(const fx4*)&Af[(size_t)(brow + row) * DIM + k0 + c8 + 4];
        bf16* ap = (bf16*)&a;
        #pragma unroll
        for (int j = 0; j < 4; ++j) { ap[j] = __float2bfloat16(a0[j]); ap[4 + j] = __float2bfloat16(a1[j]); }
      }
      {
        fx4 b0 = *(const fx4*)&Wf[(size_t)(bcol + row) * DIM + k0 + c8];
        fx4 b1 = *(const fx4*)&Wf[(size_t)(bcol + row) * DIM + k0 + c8 + 4];
        bf16* bp = (bf16*)&b;
        #pragma unroll
        for (int j = 0; j < 4; ++j) { bp[j] = __float2bfloat16(b0[j]); bp[4 + j] = __float2bfloat16(b1[j]); }
      }
      *(s16x8*)&As[row * 64 + c8] = a;
      *(s16x8*)&Bs[row * 64 + c8] = b;
    }
    __syncthreads();
    #pragma unroll
    for (int kk = 0; kk < 2; ++kk) {
      s16x8 af[4], bfr[4];
      #pragma unroll
      for (int mi = 0; mi < 4; ++mi)
        af[mi] = *(const s16x8*)&As[(wr * 64 + mi * 16 + l15) * 64 + kk * 32 + lg * 8];
      #pragma unroll
      for (int nj = 0; nj < 4; ++nj)
        bfr[nj] = *(const s16x8*)&Bs[(wc * 64 + nj * 16 + l15) * 64 + kk * 32 + lg * 8];
      #pragma unroll
      for (int mi = 0; mi < 4; ++mi)
        #pragma unroll
        for (int nj = 0; nj < 4; ++nj)
          acc[mi][nj] = MFMA_BF16(af[mi], bfr[nj], acc[mi][nj]);
    }
    __syncthreads();
  }

  #pragma unroll
  for (int mi = 0; mi < 4; ++mi) {
    const int mbase = brow + wr * 64 + mi * 16 + lg * 4;
    #pragma unroll
    for (int nj = 0; nj < 4; ++nj) {
      const int n = bcol + wc * 64 + nj * 16 + l15;
      const float bv = bias[n];
      #pragma unroll
      for (int r = 0; r < 4; ++r) {
        const int m = mbase + r;
        float val = acc[mi][nj][r] + bv;
        if (mode <= 1) {
          const float pv = __shfl_xor(val, 1);
          const int sp = m & (SEQ - 1);
          const int fi = (n >> 1) & 63;
          const float c = fcos[sp * 64 + fi];
          const float s = fsin[sp * 64 + fi];
          val = (n & 1) ? (pv * s + val * c) : (val * c - pv * s);
        }
        if (mode == 3) {
          ((float*)outv)[(size_t)m * DIM + n] = val;
        } else {
          const int b = m >> 11, sp = m & (SEQ - 1);
          const int h = n >> 7, d = n & (HD - 1);
          ((bf16*)outv)[((size_t)(b * NH + h) * SEQ + sp) * HD + d] = __float2bfloat16(val);
        }
      }
    }
  }
}

// ---------------- causal flash attention (R10 shape + T14 reg-staged prefetch) ----
// 64KB LDS, 2 blocks/CU (proven L2-friendly). Staging via global->reg->LDS:
// tile kt+1 loads are issued right after B1 and fly during QK/softmax/PV.
#define SOFTMAX_PHASE(sa, o, mrun, lrun, q0)                                   \
  {                                                                            \
    _Pragma("unroll")                                                          \
    for (int r = 0; r < 4; ++r) {                                              \
      const int q = (q0) + lg * 4 + r;                                         \
      float mx = -__builtin_inff();                                            \
      _Pragma("unroll")                                                        \
      for (int nj = 0; nj < 4; ++nj) {                                         \
        float v = sa[nj][r] * scale;                                           \
        if (diagM && (t0 + nj * 16 + l15 > q)) v = -__builtin_inff();          \
        sa[nj][r] = v;                                                         \
        mx = fmaxf(mx, v);                                                     \
      }                                                                        \
      _Pragma("unroll")                                                        \
      for (int off = 1; off < 16; off <<= 1) mx = fmaxf(mx, __shfl_xor(mx, off)); \
      const float mnew = fmaxf(mrun[r], mx);                                   \
      const float fsc = __expf(mrun[r] - mnew);                                \
      mrun[r] = mnew;                                                          \
      float rs = 0.f;                                                          \
      _Pragma("unroll")                                                        \
      for (int nj = 0; nj < 4; ++nj) {                                         \
        const float pp = __expf(sa[nj][r] - mnew);                             \
        sa[nj][r] = pp;                                                        \
        rs += pp;                                                              \
      }                                                                        \
      _Pragma("unroll")                                                        \
      for (int off = 1; off < 16; off <<= 1) rs += __shfl_xor(rs, off);        \
      lrun[r] = lrun[r] * fsc + rs;                                            \
      _Pragma("unroll")                                                        \
      for (int dj = 0; dj < 8; ++dj) o[dj][r] *= fsc;                          \
    }                                                                          \
  }

__global__ __launch_bounds__(256, 2)
void attn_fwd(const bf16* __restrict__ Q, const bf16* __restrict__ K,
              const bf16* __restrict__ V, bf16* __restrict__ ymat)
{
  __shared__ __align__(16) bf16 smem[32768];   // 64 KB
  bf16* Kl   = smem;                  // [64][128]  16 KB
  bf16* Vrow = smem + 8192;           // [64][128]  16 KB
  bf16* Vt   = smem + 16384;          // [128][64]  16 KB
  bf16* PlA  = smem + 24576;          // 4x[16][64]  8 KB
  bf16* PlB  = smem + 28672;          // 4x[16][64]  8 KB
  bf16* Ys   = smem;                  // epilogue alias [64][256] 32 KB

  const int tid = threadIdx.x, wid = tid >> 6, lane = tid & 63;
  const int l15 = lane & 15, lg = lane >> 4;
  const int pair = blockIdx.x, bh = blockIdx.y;
  const int qtA = pair, qtB = 31 - pair;
  const int b = bh >> 5, h = bh & 31;
  const bf16* Qb = Q + (size_t)bh * SEQ * HD;
  const bf16* Kb = K + (size_t)bh * SEQ * HD;
  const bf16* Vb = V + (size_t)bh * SEQ * HD;
  const int q0A = qtA * 64 + wid * 16;
  const int q0B = qtB * 64 + wid * 16;

  s16x8 aqA[4], aqB[4];
  #pragma unroll
  for (int kk = 0; kk < 4; ++kk) {
    aqA[kk] = *(const s16x8*)&Qb[(size_t)(q0A + l15) * HD + kk * 32 + lg * 8];
    aqB[kk] = *(const s16x8*)&Qb[(size_t)(q0B + l15) * HD + kk * 32 + lg * 8];
  }

  fx4 oA[8] = {}, oB[8] = {};
  float mA[4], lA[4], mB[4], lB[4];
  #pragma unroll
  for (int r = 0; r < 4; ++r) {
    mA[r] = -__builtin_inff(); lA[r] = 0.f;
    mB[r] = -__builtin_inff(); lB[r] = 0.f;
  }
  const float scale = 0.08838834764831845f;

  // per-thread staging address components (4 chunks/thread, 16B each for K and V)
  // chunk = i*4+wid ; row = chunk*4+lg ; src col = (l15 ^ (row&7))*8 ; dst = chunk*1024B + lane*16B
  s16x8 kreg[4], vreg[4];
  #pragma unroll
  for (int i = 0; i < 4; ++i) {
    const int chunk = i * 4 + wid;
    const int row = chunk * 4 + lg;
    const int col = ((l15 ^ (row & 7)) * 8);
    kreg[i] = *(const s16x8*)&Kb[(size_t)row * HD + col];
    vreg[i] = *(const s16x8*)&Vb[(size_t)row * HD + col];
  }

  for (int kt = 0; kt <= qtB; ++kt) {
    const int t0 = kt * 64;
    const bool doA = (kt <= qtA);     // block-uniform

    // write staged regs (tile kt) into LDS
    #pragma unroll
    for (int i = 0; i < 4; ++i) {
      const int chunk = i * 4 + wid;
      *(s16x8*)((char*)Kl + chunk * 1024 + lane * 16) = kreg[i];
      *(s16x8*)((char*)Vrow + chunk * 1024 + lane * 16) = vreg[i];
    }
    __syncthreads();   // B1

    // prefetch tile kt+1 into regs — flies under the compute below
    if (kt < qtB) {
      const int t1 = t0 + 64;
      #pragma unroll
      for (int i = 0; i < 4; ++i) {
        const int chunk = i * 4 + wid;
        const int row = chunk * 4 + lg;
        const int col = ((l15 ^ (row & 7)) * 8);
        kreg[i] = *(const s16x8*)&Kb[(size_t)(t1 + row) * HD + col];
        vreg[i] = *(const s16x8*)&Vb[(size_t)(t1 + row) * HD + col];
      }
    }

    // QK^T for both q-sets
    fx4 sA[4], sB[4];
    #pragma unroll
    for (int nj = 0; nj < 4; ++nj) {
      fx4 sa = {}, sb = {};
      #pragma unroll
      for (int kk = 0; kk < 4; ++kk) {
        const int trow = nj * 16 + l15;
        const int colp = (kk * 32 + lg * 8) ^ ((trow & 7) << 3);
        s16x8 bk = *(const s16x8*)&Kl[trow * HD + colp];
        sb = MFMA_BF16(aqB[kk], bk, sb);
        if (doA) sa = MFMA_BF16(aqA[kk], bk, sa);
      }
      sB[nj] = sb; sA[nj] = sa;
    }

    // V transpose Vrow -> Vt
    #pragma unroll
    for (int it = 0; it < 2; ++it) {
      const int p = lane;
      const int tg = it * 4 + wid;
      s16x8 lo, hi; bf16* lop = (bf16*)&lo; bf16* hip = (bf16*)&hi;
      #pragma unroll
      for (int j = 0; j < 8; ++j) {
        const int t = tg * 8 + j;
        const u32 v32 = *(const u32*)((const char*)Vrow + t * 256 + ((p * 4) ^ (j << 4)));
        lop[j] = ((const bf16*)&v32)[0];
        hip[j] = ((const bf16*)&v32)[1];
      }
      *(s16x8*)((char*)Vt + (2 * p) * 128 + ((tg * 16) ^ ((p & 7) << 4))) = lo;
      *(s16x8*)((char*)Vt + (2 * p + 1) * 128 + ((tg * 16) ^ ((p & 7) << 4))) = hi;
    }

    // softmax + P writes
    {
      const bool diagM = (kt == qtB);
      SOFTMAX_PHASE(sB, oB, mB, lB, q0B)
      #pragma unroll
      for (int r = 0; r < 4; ++r) {
        const int row = lg * 4 + r;
        #pragma unroll
        for (int nj = 0; nj < 4; ++nj) {
          const int colp = (nj * 16 + l15) ^ ((row & 7) << 3);
          PlB[wid * 1024 + row * 64 + colp] = __float2bfloat16(sB[nj][r]);
        }
      }
    }
    if (doA) {
      const bool diagM = (kt == qtA);
      SOFTMAX_PHASE(sA, oA, mA, lA, q0A)
      #pragma unroll
      for (int r = 0; r < 4; ++r) {
        const int row = lg * 4 + r;
        #pragma unroll
        for (int nj = 0; nj < 4; ++nj) {
          const int colp = (nj * 16 + l15) ^ ((row & 7) << 3);
          PlA[wid * 1024 + row * 64 + colp] = __float2bfloat16(sA[nj][r]);
        }
      }
    }
    __syncthreads();   // B2

    // PV
    s16x8 paA[2], paB[2];
    #pragma unroll
    for (int k2 = 0; k2 < 2; ++k2) {
      const int colp = (k2 * 32 + lg * 8) ^ ((l15 & 7) << 3);
      paB[k2] = *(const s16x8*)&PlB[wid * 1024 + l15 * 64 + colp];
      if (doA) paA[k2] = *(const s16x8*)&PlA[wid * 1024 + l15 * 64 + colp];
    }
    #pragma unroll
    for (int dj = 0; dj < 8; ++dj) {
      const int d = dj * 16 + l15;
      #pragma unroll
      for (int k2 = 0; k2 < 2; ++k2) {
        const int colp = (k2 * 32 + lg * 8) ^ (((d >> 1) & 7) << 3);
        s16x8 bv = *(const s16x8*)&Vt[d * 64 + colp];
        oB[dj] = MFMA_BF16(paB[k2], bv, oB[dj]);
        if (doA) oA[dj] = MFMA_BF16(paA[k2], bv, oA[dj]);
      }
    }
    __syncthreads();   // B3
  }

  // epilogue: LDS-staged, full-line ymat writes
  #pragma unroll
  for (int dj = 0; dj < 8; ++dj) {
    const int d = dj * 16 + l15;
    const int lr = d >> 1;
    const int cbase = (d & 1) * 128 + wid * 16 + lg * 4;
    const int sw = (lr & 7) << 3;
    #pragma unroll
    for (int r = 0; r < 4; ++r) {
      Ys[lr * 256 + ((cbase + r) ^ sw)]       = __float2bfloat16(oA[dj][r] / lA[r]);
      Ys[lr * 256 + ((cbase + 64 + r) ^ sw)]  = __float2bfloat16(oB[dj][r] / lB[r]);
    }
  }
  __syncthreads();

  const size_t growbase = (size_t)(b * SEQ + h * 64) * DIM;
  #pragma unroll
  for (int it = 0; it < 8; ++it) {
    const int f = it * 256 + tid;
    const int lr = f >> 5;
    const int cu = f & 31;
    s16x8 v = *(const s16x8*)&Ys[lr * 256 + ((cu ^ (lr & 7)) << 3)];
    const int seg = cu >> 3;
    const int off = (cu & 7) * 8;
    const int par = seg >> 1, ab = seg & 1;
    const int qbase = (ab ? qtB : qtA) * 64;
    *(s16x8*)&ymat[growbase + (size_t)lr * DIM + par * 2048 + qbase + off] = v;
  }
}

extern "C" void kernel_launch(void* const* d_in, const int* in_sizes, int n_in,
                              void* d_out, int out_size, void* d_ws, size_t ws_size,
                              hipStream_t stream)
{
  (void)in_sizes; (void)n_in; (void)out_size;
  const float* x  = (const float*)d_in[0];
  const float* wq = (const float*)d_in[1];
  const float* bq = (const float*)d_in[2];
  const float* wk = (const float*)d_in[3];
  const float* bk = (const float*)d_in[4];
  const float* wv = (const float*)d_in[5];
  const float* bv = (const float*)d_in[6];
  const float* wo = (const float*)d_in[7];
  const float* bo = (const float*)d_in[8];
  const float* fc = (const float*)d_in[9];
  const float* fs = (const float*)d_in[10];

  const size_t NE = (size_t)2 * SEQ * DIM;
  const size_t NW = (size_t)DIM * DIM;
  const size_t SLOT = NE * sizeof(bf16);
  const size_t NEED_FAST = 6 * SLOT + 256;
  const size_t NEED_SLOW = 4 * SLOT + 256;

  dim3 blk(256);
  if (ws_size >= NEED_FAST) {
    bf16* xb = (bf16*)((char*)d_ws + 256);
    bf16* wb = xb + NE;
    bf16* qb = wb + NW;
    bf16* kb = qb + NE;
    bf16* vb = kb + NE;
    bf16* ym = vb + NE;
    const int n8x = (int)(NE / 8), n8w = (int)(NW / 8);
    dim3 cg(2048);
    dim3 blk2(512), gg2(16, 16);
    hipLaunchKernelGGL(cvt_f32_bf16, cg, blk, 0, stream, x, xb, n8x);
    hipLaunchKernelGGL(cvt_f32_bf16, cg, blk, 0, stream, wq, wb, n8w);
    hipLaunchKernelGGL(gemm256, gg2, blk2, 0, stream, xb, wb, bq, fc, fs, qb, 0);
    hipLaunchKernelGGL(cvt_f32_bf16, cg, blk, 0, stream, wk, wb, n8w);
    hipLaunchKernelGGL(gemm256, gg2, blk2, 0, stream, xb, wb, bk, fc, fs, kb, 1);
    hipLaunchKernelGGL(cvt_f32_bf16, cg, blk, 0, stream, wv, wb, n8w);
    hipLaunchKernelGGL(gemm256, gg2, blk2, 0, stream, xb, wb, bv, fc, fs, vb, 2);
    hipLaunchKernelGGL(attn_fwd, dim3(16, 64), blk, 0, stream, qb, kb, vb, ym);
    hipLaunchKernelGGL(cvt_f32_bf16, cg, blk, 0, stream, wo, wb, n8w);
    hipLaunchKernelGGL(gemm256, gg2, blk2, 0, stream, ym, wb, bo, fc, fs, d_out, 3);
  } else if (ws_size >= NEED_SLOW) {
    bf16* qb = (bf16*)((char*)d_ws + 256);
    bf16* kb = qb + NE;
    bf16* vb = kb + NE;
    bf16* ym = vb + NE;
    dim3 gg(32, 32);
    hipLaunchKernelGGL(gemm_slow, gg, blk, 0, stream, x, wq, bq, fc, fs, qb, 0);
    hipLaunchKernelGGL(gemm_slow, gg, blk, 0, stream, x, wk, bk, fc, fs, kb, 1);
    hipLaunchKernelGGL(gemm_slow, gg, blk, 0, stream, x, wv, bv, fc, fs, vb, 2);
    hipLaunchKernelGGL(attn_fwd, dim3(16, 64), blk, 0, stream, qb, kb, vb, ym);
    hipLaunchKernelGGL(gemm_slow, gg, blk, 0, stream, ym, wo, bo, fc, fs, d_out, 3);
  }
}